// Round 7
// baseline (722.082 us; speedup 1.0000x reference)
//
#include <hip/hip_runtime.h>

#define N_NODES 50000
#define N_EDGES 600000
#define HC 256
#define NH 8
#define AGG_BLOCKS 2048
#define AGG_WAVES (AGG_BLOCKS * 4)
#define ASD_N (N_NODES * NH * 2)   // as_ + ad_ floats

typedef short s8v __attribute__((ext_vector_type(8)));
typedef float f4v __attribute__((ext_vector_type(4)));
typedef _Float16 h4v __attribute__((ext_vector_type(4)));
typedef _Float16 h2v __attribute__((ext_vector_type(2)));
typedef __attribute__((address_space(1))) const unsigned int as1_cu32;
typedef __attribute__((address_space(3))) unsigned int as3_u32;

__device__ inline ushort f2bf(float f) {
  unsigned u = __float_as_uint(f);
  unsigned r = u + 0x7FFF + ((u >> 16) & 1);  // RNE
  return (ushort)(r >> 16);
}

// ---------------------------------------------------------------- CSR build
__global__ void k_init_cnt(int* __restrict__ cnt) {
  int i = blockIdx.x * 256 + threadIdx.x;
  if (i < N_NODES) cnt[i] = 1;  // self-loop
}

__global__ void k_count(const int* __restrict__ dstE, int* __restrict__ cnt) {
  int e = blockIdx.x * 256 + threadIdx.x;
  if (e < N_EDGES) atomicAdd(&cnt[dstE[e]], 1);
}

__global__ void k_scan_bsum(const int* __restrict__ cnt, int* __restrict__ bsum) {
  __shared__ int sd[256];
  int i = blockIdx.x * 256 + threadIdx.x;
  sd[threadIdx.x] = (i < N_NODES) ? cnt[i] : 0;
  __syncthreads();
  for (int o = 128; o > 0; o >>= 1) {
    if (threadIdx.x < o) sd[threadIdx.x] += sd[threadIdx.x + o];
    __syncthreads();
  }
  if (threadIdx.x == 0) bsum[blockIdx.x] = sd[0];
}

__global__ void k_scan_offsets(int* __restrict__ bsum, int nb) {
  __shared__ int s[256];
  int t = threadIdx.x;
  int v = (t < nb) ? bsum[t] : 0;
  s[t] = v; __syncthreads();
  for (int o = 1; o < 256; o <<= 1) {
    int x = (t >= o) ? s[t - o] : 0;
    __syncthreads();
    s[t] += x;
    __syncthreads();
  }
  if (t < nb) bsum[t] = s[t] - v;  // exclusive
}

__global__ void k_scan_write(const int* __restrict__ cnt, const int* __restrict__ bsum,
                             int* __restrict__ rowptr, int* __restrict__ fillptr) {
  __shared__ int s[256];
  int t = threadIdx.x;
  int i = blockIdx.x * 256 + t;
  int v = (i < N_NODES) ? cnt[i] : 0;
  s[t] = v; __syncthreads();
  for (int o = 1; o < 256; o <<= 1) {
    int x = (t >= o) ? s[t - o] : 0;
    __syncthreads();
    s[t] += x;
    __syncthreads();
  }
  int excl = s[t] - v + bsum[blockIdx.x];
  if (i < N_NODES) {
    rowptr[i] = excl;
    fillptr[i] = excl;
    if (i == N_NODES - 1) rowptr[N_NODES] = excl + v;
  }
}

__global__ void k_fill(const int* __restrict__ srcE, const int* __restrict__ dstE,
                       int* __restrict__ fillptr, int* __restrict__ srcs) {
  int i = blockIdx.x * 256 + threadIdx.x;
  if (i < N_NODES) {
    int pos = atomicAdd(&fillptr[i], 1);
    srcs[pos] = i;                       // self-loop
  } else if (i < N_NODES + N_EDGES) {
    int e = i - N_NODES;
    int pos = atomicAdd(&fillptr[dstE[e]], 1);
    srcs[pos] = srcE[e];
  }
}

// ---------------------------------------------------------------- fp32 -> bf16 converts
// also zeroes the as_/ad_ logit buffer for the first fused-att GEMM
__global__ void k_cvt_x(const float* __restrict__ X, ushort* __restrict__ Xb,
                        float* __restrict__ asd) {
  int gid = blockIdx.x * 256 + threadIdx.x;
  if (gid < ASD_N) asd[gid] = 0.f;
  size_t i = (size_t)gid * 4;
  float4 x4 = *(const float4*)&X[i];
  ushort4 o;
  o.x = f2bf(x4.x); o.y = f2bf(x4.y); o.z = f2bf(x4.z); o.w = f2bf(x4.w);
  *(ushort4*)&Xb[i] = o;
}

// W[K][Nw] fp32 -> Wt[Nw][K] bf16 (transpose + convert)
__global__ void k_cvt_wt(const float* __restrict__ W, ushort* __restrict__ Wt, int K, int Nw) {
  __shared__ ushort s[32][33];
  int tx = threadIdx.x & 31, ty = threadIdx.x >> 5;
  int k0 = blockIdx.x * 32, n0 = blockIdx.y * 32;
  for (int j = 0; j < 32; j += 8)
    s[ty + j][tx] = f2bf(W[(size_t)(k0 + ty + j) * Nw + n0 + tx]);
  __syncthreads();
  for (int j = 0; j < 32; j += 8)
    Wt[(size_t)(n0 + ty + j) * K + k0 + tx] = s[tx][ty + j];
}

// pack [muW | lvW | auxW | 0] -> Wth[128][256] bf16
__global__ void k_pack_head(const float* __restrict__ muW, const float* __restrict__ lvW,
                            const float* __restrict__ auxW, ushort* __restrict__ Wth) {
  int n = blockIdx.x;   // 0..127
  int k = threadIdx.x;  // 0..255
  float v = 0.f;
  if (n < 32) v = muW[k * 32 + n];
  else if (n < 64) v = lvW[k * 32 + (n - 32)];
  else if (n < 94) v = auxW[k * 30 + (n - 64)];
  Wth[n * 256 + k] = f2bf(v);
}

// ---------------------------------------------------------------- bf16 MFMA GEMM (m97-style)
// ATT: fuse attention-logit partials (per-row dot with asrc/adst, 16-lane shuffle
//      reduce, atomicAdd into as_g/ad_g — caller must pre-zero).
// RES: grid.y = 4; y>=2 computes the residual GEMM (Wt2/bias2/Out2), no att.
template <typename OutT, bool ATT, bool RES>
__launch_bounds__(256)
__global__ void k_gemm_bf16(const ushort* __restrict__ A, const ushort* __restrict__ Wt,
                            const float* __restrict__ bias, OutT* __restrict__ Out,
                            int M, int K, int ldc,
                            const float* __restrict__ asrcf, const float* __restrict__ adstf,
                            float* __restrict__ as_g, float* __restrict__ ad_g,
                            const ushort* __restrict__ Wt2, const float* __restrict__ bias2,
                            OutT* __restrict__ Out2) {
  __shared__ __align__(16) ushort As[16 * 512];  // 16 KB
  __shared__ __align__(16) ushort Bs[16 * 512];  // 16 KB
  int t = threadIdx.x, w = t >> 6, L = t & 63;
  int bm = blockIdx.x * 128;
  int bn = blockIdx.y * 128;
  const ushort* Wsel = Wt;
  const float* bsel = bias;
  OutT* Osel = Out;
  bool doatt = ATT;
  if (RES && blockIdx.y >= 2) {
    Wsel = Wt2; bsel = bias2; Osel = Out2;
    bn = (blockIdx.y - 2) * 128;
    doatt = false;
  }
  int lrow = L & 15, lcol = (L >> 4) * 8;

  const ushort* ga[4];
  const ushort* gb[4];
#pragma unroll
  for (int u = 0; u < 4; u++) {
    int i = w * 4 + u;
    int mt = i >> 1, ks = i & 1;
    int arow = bm + mt * 16 + lrow;
    if (arow >= M) arow = M - 1;
    ga[u] = A + (size_t)arow * K + ks * 32 + lcol;
    int brow = bn + mt * 16 + lrow;
    gb[u] = Wsel + (size_t)brow * K + ks * 32 + lcol;
  }

  f4v acc[4][4];
  f4v zero = {0.f, 0.f, 0.f, 0.f};
#pragma unroll
  for (int mi = 0; mi < 4; mi++)
#pragma unroll
    for (int ni = 0; ni < 4; ni++) acc[mi][ni] = zero;

  int wm = (w >> 1) * 4;
  int wn = (w & 1) * 4;

  int nk = K >> 6;
  for (int kt = 0; kt < nk; kt++) {
#pragma unroll
    for (int u = 0; u < 4; u++) {
      int i = w * 4 + u;
      __builtin_amdgcn_global_load_lds((as1_cu32*)ga[u], (as3_u32*)&As[i * 512], 16, 0, 0);
      __builtin_amdgcn_global_load_lds((as1_cu32*)gb[u], (as3_u32*)&Bs[i * 512], 16, 0, 0);
      ga[u] += 64; gb[u] += 64;
    }
    __syncthreads();
#pragma unroll
    for (int ks = 0; ks < 2; ks++) {
      s8v af[4], bf[4];
#pragma unroll
      for (int mi = 0; mi < 4; mi++)
        af[mi] = *(const s8v*)&As[(((wm + mi) * 2 + ks) * 64 + L) * 8];
#pragma unroll
      for (int ni = 0; ni < 4; ni++)
        bf[ni] = *(const s8v*)&Bs[(((wn + ni) * 2 + ks) * 64 + L) * 8];
#pragma unroll
      for (int mi = 0; mi < 4; mi++)
#pragma unroll
        for (int ni = 0; ni < 4; ni++)
          acc[mi][ni] = __builtin_amdgcn_mfma_f32_16x16x32_bf16(af[mi], bf[ni], acc[mi][ni], 0, 0, 0);
    }
    __syncthreads();
  }
  // epilogue stores: C/D layout col=lane&15, row=(lane>>4)*4+i
#pragma unroll
  for (int ni = 0; ni < 4; ni++) {
    int col = bn + (wn + ni) * 16 + (L & 15);
    float bb = bsel ? bsel[col] : 0.f;
#pragma unroll
    for (int mi = 0; mi < 4; mi++) {
      int rbase = bm + (wm + mi) * 16 + (L >> 4) * 4;
#pragma unroll
      for (int i = 0; i < 4; i++) {
        int r = rbase + i;
        if (r < M) Osel[(size_t)r * ldc + col] = (OutT)(acc[mi][ni][i] + bb);
      }
    }
  }
  // fused attention-logit partials
  if (ATT && doatt) {
    int l = L & 15, q = L >> 4;
    int base = bn + wn * 16;  // multiple of 32 -> 2 heads covered (base/32, base/32+1)
    int h0 = base >> 5;
    float sa0 = asrcf[base + l],      sa1 = asrcf[base + 16 + l];
    float sa2 = asrcf[base + 32 + l], sa3 = asrcf[base + 48 + l];
    float da0 = adstf[base + l],      da1 = adstf[base + 16 + l];
    float da2 = adstf[base + 32 + l], da3 = adstf[base + 48 + l];
#pragma unroll
    for (int mi = 0; mi < 4; mi++) {
#pragma unroll
      for (int i = 0; i < 4; i++) {
        float pas0 = acc[mi][0][i] * sa0 + acc[mi][1][i] * sa1;
        float pas1 = acc[mi][2][i] * sa2 + acc[mi][3][i] * sa3;
        float pad0 = acc[mi][0][i] * da0 + acc[mi][1][i] * da1;
        float pad1 = acc[mi][2][i] * da2 + acc[mi][3][i] * da3;
#pragma unroll
        for (int o = 1; o <= 8; o <<= 1) {
          pas0 += __shfl_xor(pas0, o); pas1 += __shfl_xor(pas1, o);
          pad0 += __shfl_xor(pad0, o); pad1 += __shfl_xor(pad1, o);
        }
        if (l == 0) {
          int r = bm + (wm + mi) * 16 + q * 4 + i;
          if (r < M) {
            atomicAdd(&as_g[r * NH + h0], pas0);
            atomicAdd(&as_g[r * NH + h0 + 1], pas1);
            atomicAdd(&ad_g[r * NH + h0], pad0);
            atomicAdd(&ad_g[r * NH + h0 + 1], pad1);
          }
        }
      }
    }
  }
}

// ---------------------------------------------------------------- aggregate (single pass) + BN partials
// persistent grid; one wave / node; unnormalized packed-fp16 accumulate, divide once.
__launch_bounds__(256)
__global__ void k_agg(const int* __restrict__ rowptr, const int* __restrict__ srcs,
                      const float* __restrict__ as_, const float* __restrict__ ad_,
                      const _Float16* __restrict__ B, const float* __restrict__ gb,
                      _Float16* __restrict__ C, float* __restrict__ part,
                      float* __restrict__ stats) {
  __shared__ float ss[4 * 512];
  int t = threadIdx.x;
  if (blockIdx.x == 0) {  // stats consumed only by k_bn_reduce (after this kernel)
    stats[t] = 0.f; stats[t + 256] = 0.f;
  }
  int w = t >> 6, lane = t & 63;
  int h = lane >> 3;
  int cb = lane << 2;  // 4 channels per lane
  float4 g4 = *(const float4*)&gb[cb];
  float sts0 = 0.f, sts1 = 0.f, sts2 = 0.f, sts3 = 0.f;
  float stq0 = 0.f, stq1 = 0.f, stq2 = 0.f, stq3 = 0.f;

  for (int n = blockIdx.x * 4 + w; n < N_NODES; n += AGG_WAVES) {
    int beg = rowptr[n], end = rowptr[n + 1];
    float ad_nh = ad_[n * NH + h];
    h2v a01 = {(_Float16)0, (_Float16)0};
    h2v a23 = {(_Float16)0, (_Float16)0};
    float wsum = 0.f;
    int k = beg;
    for (; k + 4 <= end; k += 4) {
      int s0 = srcs[k], s1 = srcs[k + 1], s2 = srcs[k + 2], s3 = srcs[k + 3];
      h4v b0 = *(const h4v*)&B[(size_t)s0 * 256 + cb];
      h4v b1 = *(const h4v*)&B[(size_t)s1 * 256 + cb];
      h4v b2 = *(const h4v*)&B[(size_t)s2 * 256 + cb];
      h4v b3 = *(const h4v*)&B[(size_t)s3 * 256 + cb];
      float e0 = as_[s0 * NH + h] + ad_nh; e0 = e0 > 0.f ? e0 : 0.2f * e0;
      float e1 = as_[s1 * NH + h] + ad_nh; e1 = e1 > 0.f ? e1 : 0.2f * e1;
      float e2 = as_[s2 * NH + h] + ad_nh; e2 = e2 > 0.f ? e2 : 0.2f * e2;
      float e3 = as_[s3 * NH + h] + ad_nh; e3 = e3 > 0.f ? e3 : 0.2f * e3;
      float p0 = __expf(e0), p1 = __expf(e1), p2 = __expf(e2), p3 = __expf(e3);
      wsum += (p0 + p1) + (p2 + p3);
      _Float16 q0 = (_Float16)p0, q1 = (_Float16)p1, q2 = (_Float16)p2, q3 = (_Float16)p3;
      h2v pp0 = {q0, q0}, pp1 = {q1, q1}, pp2 = {q2, q2}, pp3 = {q3, q3};
      h2v b0l = __builtin_shufflevector(b0, b0, 0, 1), b0h = __builtin_shufflevector(b0, b0, 2, 3);
      h2v b1l = __builtin_shufflevector(b1, b1, 0, 1), b1h = __builtin_shufflevector(b1, b1, 2, 3);
      h2v b2l = __builtin_shufflevector(b2, b2, 0, 1), b2h = __builtin_shufflevector(b2, b2, 2, 3);
      h2v b3l = __builtin_shufflevector(b3, b3, 0, 1), b3h = __builtin_shufflevector(b3, b3, 2, 3);
      a01 += pp0 * b0l + pp1 * b1l + pp2 * b2l + pp3 * b3l;
      a23 += pp0 * b0h + pp1 * b1h + pp2 * b2h + pp3 * b3h;
    }
    for (; k < end; k++) {
      int s = srcs[k];
      h4v b4 = *(const h4v*)&B[(size_t)s * 256 + cb];
      float e = as_[s * NH + h] + ad_nh;
      e = e > 0.f ? e : 0.2f * e;
      float p = __expf(e);
      wsum += p;
      _Float16 qq = (_Float16)p;
      h2v pp = {qq, qq};
      a01 += pp * __builtin_shufflevector(b4, b4, 0, 1);
      a23 += pp * __builtin_shufflevector(b4, b4, 2, 3);
    }
    float inv = 1.f / (wsum + 1e-16f);
    float v0 = (float)a01[0] * inv + g4.x, v1 = (float)a01[1] * inv + g4.y;
    float v2 = (float)a23[0] * inv + g4.z, v3 = (float)a23[1] * inv + g4.w;
    h4v o; o[0] = (_Float16)v0; o[1] = (_Float16)v1; o[2] = (_Float16)v2; o[3] = (_Float16)v3;
    *(h4v*)&C[(size_t)n * 256 + cb] = o;
    sts0 += v0; stq0 += v0 * v0;
    sts1 += v1; stq1 += v1 * v1;
    sts2 += v2; stq2 += v2 * v2;
    sts3 += v3; stq3 += v3 * v3;
  }
  // per-wave LDS slots, cross-wave sum, plain store of partials (no hot atomics)
  float* sw = &ss[w * 512];
  sw[cb + 0] = sts0; sw[cb + 1] = sts1; sw[cb + 2] = sts2; sw[cb + 3] = sts3;
  sw[256 + cb + 0] = stq0; sw[256 + cb + 1] = stq1;
  sw[256 + cb + 2] = stq2; sw[256 + cb + 3] = stq3;
  __syncthreads();
  float p0 = ss[t] + ss[512 + t] + ss[1024 + t] + ss[1536 + t];
  float p1 = ss[256 + t] + ss[768 + t] + ss[1280 + t] + ss[1792 + t];
  part[(size_t)blockIdx.x * 512 + t] = p0;
  part[(size_t)blockIdx.x * 512 + 256 + t] = p1;
}

// reduce AGG_BLOCKS x 512 partials -> stats[512]; also zero as_/ad_ for next layer's
// fused-att GEMM. 128 blocks.
__global__ void k_bn_reduce(const float* __restrict__ part, float* __restrict__ stats,
                            float* __restrict__ asd) {
  int i = threadIdx.x;            // 0..255
  int base = blockIdx.x * (AGG_BLOCKS / 128);
  float s0 = 0.f, s1 = 0.f;
  for (int b = 0; b < AGG_BLOCKS / 128; b++) {
    s0 += part[(size_t)(base + b) * 512 + i];
    s1 += part[(size_t)(base + b) * 512 + 256 + i];
  }
  atomicAdd(&stats[i], s0);
  atomicAdd(&stats[256 + i], s1);
  for (int z = blockIdx.x * 256 + i; z < ASD_N; z += 128 * 256) asd[z] = 0.f;
}

// BN + ReLU (+ optional fp16 residual add): fp16 in -> bf16 out
__global__ void k_bn_relu_cvt(const _Float16* __restrict__ X, const float* __restrict__ stats,
                              const float* __restrict__ g, const float* __restrict__ b,
                              const _Float16* __restrict__ resid, ushort* __restrict__ Xb) {
  size_t i = ((size_t)blockIdx.x * 256 + threadIdx.x) * 4;
  int c = (int)(i & 255);
  const float invN = 1.f / (float)N_NODES;
  h4v x4 = *(const h4v*)&X[i];
  float4 s4 = *(const float4*)&stats[c];
  float4 q4 = *(const float4*)&stats[256 + c];
  float4 g4 = *(const float4*)&g[c];
  float4 b4 = *(const float4*)&b[c];
  float m0 = s4.x * invN, m1 = s4.y * invN, m2 = s4.z * invN, m3 = s4.w * invN;
  float v0 = ((float)x4[0] - m0) * rsqrtf(q4.x * invN - m0 * m0 + 1e-5f) * g4.x + b4.x;
  float v1 = ((float)x4[1] - m1) * rsqrtf(q4.y * invN - m1 * m1 + 1e-5f) * g4.y + b4.y;
  float v2 = ((float)x4[2] - m2) * rsqrtf(q4.z * invN - m2 * m2 + 1e-5f) * g4.z + b4.z;
  float v3 = ((float)x4[3] - m3) * rsqrtf(q4.w * invN - m3 * m3 + 1e-5f) * g4.w + b4.w;
  v0 = v0 > 0.f ? v0 : 0.f; v1 = v1 > 0.f ? v1 : 0.f;
  v2 = v2 > 0.f ? v2 : 0.f; v3 = v3 > 0.f ? v3 : 0.f;
  if (resid) {
    h4v r4 = *(const h4v*)&resid[i];
    v0 += (float)r4[0]; v1 += (float)r4[1]; v2 += (float)r4[2]; v3 += (float)r4[3];
  }
  ushort4 ob;
  ob.x = f2bf(v0); ob.y = f2bf(v1); ob.z = f2bf(v2); ob.w = f2bf(v3);
  *(ushort4*)&Xb[i] = ob;
}

// ---------------------------------------------------------------- decode epilogue (one wave / node)
__launch_bounds__(256)
__global__ void k_dec(const _Float16* __restrict__ Hd, const float* __restrict__ eps,
                      const float* __restrict__ mub, const float* __restrict__ lvb,
                      const float* __restrict__ auxb,
                      const float* __restrict__ decW, const float* __restrict__ decb,
                      float* __restrict__ out) {
  __shared__ float wsd[2048];   // decW [32][64]
  __shared__ float shz[4][32];
  int t = threadIdx.x;
  for (int i = t; i < 2048; i += 256) wsd[i] = decW[i];
  int w = t >> 6, lane = t & 63;
  int n = blockIdx.x * 4 + w;
  const _Float16* hd = &Hd[(size_t)n * 128];
  if (lane < 32) {
    float mu = (float)hd[lane] + mub[lane];
    float lv = (float)hd[32 + lane] + lvb[lane];
    out[(size_t)N_NODES * 64 + (size_t)n * 32 + lane] = mu;
    out[(size_t)N_NODES * 96 + (size_t)n * 32 + lane] = lv;
    shz[w][lane] = mu + eps[(size_t)n * 32 + lane] * __expf(0.5f * lv);
  } else if (lane < 62) {
    int j = lane - 32;
    out[(size_t)N_NODES * 128 + (size_t)n * 30 + j] = (float)hd[64 + j] + auxb[j];
  }
  __syncthreads();
  float o = decb[lane];
#pragma unroll 8
  for (int k = 0; k < 32; k++) o += shz[w][k] * wsd[k * 64 + lane];
  out[(size_t)n * 64 + lane] = o;
}

// ---------------------------------------------------------------- launch
extern "C" void kernel_launch(void* const* d_in, const int* in_sizes, int n_in,
                              void* d_out, int out_size, void* d_ws, size_t ws_size,
                              hipStream_t stream) {
  (void)in_sizes; (void)n_in; (void)out_size; (void)ws_size;
  const float* x    = (const float*)d_in[0];
  const float* eps  = (const float*)d_in[1];
  const int*   ei   = (const int*)d_in[2];
  const float* gW[3]    = {(const float*)d_in[3],  (const float*)d_in[9],  (const float*)d_in[15]};
  const float* gasrc[3] = {(const float*)d_in[4],  (const float*)d_in[10], (const float*)d_in[16]};
  const float* gadst[3] = {(const float*)d_in[5],  (const float*)d_in[11], (const float*)d_in[17]};
  const float* gbias[3] = {(const float*)d_in[6],  (const float*)d_in[12], (const float*)d_in[18]};
  const float* bng[3]   = {(const float*)d_in[7],  (const float*)d_in[13], (const float*)d_in[19]};
  const float* bnb[3]   = {(const float*)d_in[8],  (const float*)d_in[14], (const float*)d_in[20]};
  const float* resW = (const float*)d_in[21];
  const float* resb = (const float*)d_in[22];
  const float* muW  = (const float*)d_in[23];
  const float* mub  = (const float*)d_in[24];
  const float* lvW  = (const float*)d_in[25];
  const float* lvb  = (const float*)d_in[26];
  const float* decW = (const float*)d_in[27];
  const float* decb = (const float*)d_in[28];
  const float* auxW = (const float*)d_in[29];
  const float* auxb = (const float*)d_in[30];
  float* out = (float*)d_out;

  char* ws = (char*)d_ws;
  size_t off = 0;
  auto alloc = [&](size_t bytes) -> void* {
    void* p = ws + off;
    off += (bytes + 255) & ~(size_t)255;
    return p;
  };
  _Float16* X0  = (_Float16*)alloc((size_t)N_NODES * HC * 2);  // GEMM out / att input (fp16)
  _Float16* X1  = (_Float16*)alloc((size_t)N_NODES * HC * 2);  // agg output (fp16)
  _Float16* Rr  = (_Float16*)alloc((size_t)N_NODES * HC * 2);  // residual (fp16)
  _Float16* Hd  = (_Float16*)alloc((size_t)N_NODES * 128 * 2); // head GEMM out (fp16)
  ushort* Xb    = (ushort*)alloc((size_t)N_NODES * HC * 2);    // bf16 activations
  float*  asd   = (float*)alloc((size_t)ASD_N * 4);            // as_ | ad_
  float*  as_   = asd;
  float*  ad_   = asd + (size_t)N_NODES * NH;
  float*  stats = (float*)alloc(512 * 4);
  float*  part  = (float*)alloc((size_t)AGG_BLOCKS * 512 * 4); // 4 MB BN partials
  int* cnt      = (int*)alloc((size_t)N_NODES * 4);
  int* rowptr   = (int*)alloc((size_t)(N_NODES + 1) * 4);
  int* fillptr  = (int*)alloc((size_t)N_NODES * 4);
  int* srcs     = (int*)alloc((size_t)(N_NODES + N_EDGES) * 4);
  int* bsum     = (int*)alloc(256 * 4);
  ushort* Wt1   = (ushort*)alloc(256 * 128 * 2);
  ushort* Wt2   = (ushort*)alloc(256 * 256 * 2);
  ushort* Wt3   = (ushort*)alloc(256 * 256 * 2);
  ushort* WtR   = (ushort*)alloc(256 * 128 * 2);
  ushort* Wth   = (ushort*)alloc(128 * 256 * 2);

  const int NB = (N_NODES + 255) / 256;
  // CSR build
  k_init_cnt<<<NB, 256, 0, stream>>>(cnt);
  k_count<<<(N_EDGES + 255) / 256, 256, 0, stream>>>(ei + N_EDGES, cnt);
  k_scan_bsum<<<NB, 256, 0, stream>>>(cnt, bsum);
  k_scan_offsets<<<1, 256, 0, stream>>>(bsum, NB);
  k_scan_write<<<NB, 256, 0, stream>>>(cnt, bsum, rowptr, fillptr);
  k_fill<<<(N_NODES + N_EDGES + 255) / 256, 256, 0, stream>>>(ei, ei + N_EDGES, fillptr, srcs);

  // weight prep
  k_cvt_wt<<<dim3(4, 8), 256, 0, stream>>>(gW[0], Wt1, 128, 256);
  k_cvt_wt<<<dim3(8, 8), 256, 0, stream>>>(gW[1], Wt2, 256, 256);
  k_cvt_wt<<<dim3(8, 8), 256, 0, stream>>>(gW[2], Wt3, 256, 256);
  k_cvt_wt<<<dim3(4, 8), 256, 0, stream>>>(resW, WtR, 128, 256);
  k_pack_head<<<128, 256, 0, stream>>>(muW, lvW, auxW, Wth);
  // x -> bf16 (+ zero asd for layer-1 fused att)
  k_cvt_x<<<(N_NODES * 128) / 1024, 256, 0, stream>>>(x, Xb, asd);

  const int GM = (N_NODES + 127) / 128;  // 391
  const ushort* Wts[3] = {Wt1, Wt2, Wt3};
  int K = 128;
  for (int L = 0; L < 3; L++) {
    if (L == 0) {
      // fused: y 0-1 -> gat1 GEMM + att logits, y 2-3 -> residual GEMM
      k_gemm_bf16<_Float16, true, true><<<dim3(GM, 4), 256, 0, stream>>>(
          Xb, Wts[0], nullptr, X0, N_NODES, K, 256,
          gasrc[0], gadst[0], as_, ad_, WtR, resb, Rr);
    } else {
      k_gemm_bf16<_Float16, true, false><<<dim3(GM, 2), 256, 0, stream>>>(
          Xb, Wts[L], nullptr, X0, N_NODES, K, 256,
          gasrc[L], gadst[L], as_, ad_, nullptr, nullptr, nullptr);
    }
    k_agg<<<AGG_BLOCKS, 256, 0, stream>>>(rowptr, srcs, as_, ad_, X0, gbias[L], X1, part, stats);
    k_bn_reduce<<<128, 256, 0, stream>>>(part, stats, asd);
    k_bn_relu_cvt<<<(N_NODES * HC) / 1024, 256, 0, stream>>>(
        X1, stats, bng[L], bnb[L], (L == 2) ? Rr : nullptr, Xb);
    K = 256;
  }
  // heads: Hd = h @ [muW|lvW|auxW|0] (fp16 out, no att)
  k_gemm_bf16<_Float16, false, false><<<dim3(GM, 1), 256, 0, stream>>>(
      Xb, Wth, nullptr, Hd, N_NODES, 256, 128,
      nullptr, nullptr, nullptr, nullptr, nullptr, nullptr, nullptr);
  k_dec<<<N_NODES / 4, 256, 0, stream>>>(Hd, eps, mub, lvb, auxb, decW, decb, out);
}